// Round 4
// baseline (649.959 us; speedup 1.0000x reference)
//
#include <hip/hip_runtime.h>
#include <hip/hip_bf16.h>

// SetMatchingModel S=48,N=80,D=128,H=2,HS=128.
// v4: 320-thr blocks (no spills), Wh folded into Wv (VWh), Wcs folded into
// symmetric M = Wcs_h Wcs_h^T, reg-prefetched LDS staging, 72KB LDS.

#define SS 48
#define NI 80

typedef unsigned short us;
typedef __attribute__((ext_vector_type(8))) short s8v;   // 8 bf16
typedef __attribute__((ext_vector_type(4))) float f4v;   // 4 f32

#define MFMA(a,b,c) __builtin_amdgcn_mfma_f32_16x16x32_bf16((a),(b),(c),0,0,0)

__device__ __forceinline__ float gelu_f(float x){
  return 0.5f * x * (1.0f + erff(x * 0.7071067811865475f));
}
__device__ __forceinline__ us f2b(float f){
  __hip_bfloat16 b = __float2bfloat16(f);
  return reinterpret_cast<us&>(b);
}
__device__ __forceinline__ s8v zero8(){ s8v v = {0,0,0,0,0,0,0,0}; return v; }

// ---------------- bf16 MFMA GEMM: C = gelu(A[M,K] @ B[K,N]) -----------------
template<int ABF16, int OUTF32>
__global__ __launch_bounds__(256) void mgemm_k(const void* __restrict__ Ap,
    const float* __restrict__ B, void* __restrict__ Cp, int N, int K)
{
  __shared__ __align__(16) char lds[10240]; // As[64][80B] + Bs[64][80B]
  char* As = lds; char* Bs = lds + 5120;
  const int t = threadIdx.x;
  const int wv = t >> 6, lm = t & 15, lh = (t >> 4) & 3;
  const int bx = blockIdx.x, by = blockIdx.y;
  const int ar = wv*16 + lm, r0 = wv*16 + lh*4;
  f4v acc[4];
#pragma unroll
  for (int ct = 0; ct < 4; ++ct) acc[ct] = {0.f,0.f,0.f,0.f};
  const int rA = t >> 2, kcA = (t & 3) << 3;
  const int kkB = t >> 3, nnB = (t & 7) << 3;
  for (int k0 = 0; k0 < K; k0 += 32) {
    __syncthreads();
    if (ABF16) {
      s8v v = *(const s8v*)((const us*)Ap + (size_t)(by*64 + rA)*K + k0 + kcA);
      *(s8v*)(As + rA*80 + kcA*2) = v;
    } else {
      const float* ap = (const float*)Ap + (size_t)(by*64 + rA)*K + k0 + kcA;
      float4 v0 = *(const float4*)ap, v1 = *(const float4*)(ap + 4);
      us tmp[8] = {f2b(v0.x),f2b(v0.y),f2b(v0.z),f2b(v0.w),
                   f2b(v1.x),f2b(v1.y),f2b(v1.z),f2b(v1.w)};
      *(s8v*)(As + rA*80 + kcA*2) = *(const s8v*)tmp;
    }
    {
      const float* bp = B + (size_t)(k0 + kkB)*N + bx*64 + nnB;
      float4 w0 = *(const float4*)bp, w1 = *(const float4*)(bp + 4);
      float w8[8] = {w0.x,w0.y,w0.z,w0.w,w1.x,w1.y,w1.z,w1.w};
#pragma unroll
      for (int q = 0; q < 8; ++q)
        *(us*)(Bs + (nnB + q)*80 + kkB*2) = f2b(w8[q]);
    }
    __syncthreads();
    s8v af = *(const s8v*)(As + ar*80 + lh*16);
#pragma unroll
    for (int ct = 0; ct < 4; ++ct) {
      s8v bf = *(const s8v*)(Bs + (ct*16 + lm)*80 + lh*16);
      acc[ct] = MFMA(af, bf, acc[ct]);
    }
  }
#pragma unroll
  for (int ct = 0; ct < 4; ++ct)
#pragma unroll
    for (int reg = 0; reg < 4; ++reg) {
      size_t r = by*64 + r0 + reg;
      int c = bx*64 + ct*16 + lm;
      float v = gelu_f(acc[ct][reg]);
      if (OUTF32) ((float*)Cp)[r*N + c] = v;
      else ((us*)Cp)[r*N + c] = f2b(v);
    }
}

// ---------------- fused QKV GEMM (K=128, N=256 each), V -> VT scatter -------
__global__ __launch_bounds__(256) void qkv_k(const us* __restrict__ A,
    const float* __restrict__ Wq, const float* __restrict__ Wk,
    const float* __restrict__ Wv, us* __restrict__ Qb, us* __restrict__ Kb,
    us* __restrict__ VT)
{
  __shared__ __align__(16) char lds[10240];
  char* As = lds; char* Bs = lds + 5120;
  const int t = threadIdx.x;
  const int wv = t >> 6, lm = t & 15, lh = (t >> 4) & 3;
  const int bx = blockIdx.x, by = blockIdx.y;
  const int sel = bx >> 2, bxx = bx & 3;
  const float* B = sel == 0 ? Wq : (sel == 1 ? Wk : Wv);
  const int ar = wv*16 + lm, r0 = wv*16 + lh*4;
  f4v acc[4];
#pragma unroll
  for (int ct = 0; ct < 4; ++ct) acc[ct] = {0.f,0.f,0.f,0.f};
  const int rA = t >> 2, kcA = (t & 3) << 3;
  const int kkB = t >> 3, nnB = (t & 7) << 3;
#pragma unroll
  for (int k0 = 0; k0 < 128; k0 += 32) {
    __syncthreads();
    {
      s8v v = *(const s8v*)(A + (size_t)(by*64 + rA)*128 + k0 + kcA);
      *(s8v*)(As + rA*80 + kcA*2) = v;
      const float* bp = B + (size_t)(k0 + kkB)*256 + bxx*64 + nnB;
      float4 w0 = *(const float4*)bp, w1 = *(const float4*)(bp + 4);
      float w8[8] = {w0.x,w0.y,w0.z,w0.w,w1.x,w1.y,w1.z,w1.w};
#pragma unroll
      for (int q = 0; q < 8; ++q)
        *(us*)(Bs + (nnB + q)*80 + kkB*2) = f2b(w8[q]);
    }
    __syncthreads();
    s8v af = *(const s8v*)(As + ar*80 + lh*16);
#pragma unroll
    for (int ct = 0; ct < 4; ++ct) {
      s8v bf = *(const s8v*)(Bs + (ct*16 + lm)*80 + lh*16);
      acc[ct] = MFMA(af, bf, acc[ct]);
    }
  }
  if (sel < 2) {
    us* O = sel ? Kb : Qb;
#pragma unroll
    for (int ct = 0; ct < 4; ++ct)
#pragma unroll
      for (int reg = 0; reg < 4; ++reg)
        O[(size_t)(by*64 + r0 + reg)*256 + bxx*64 + ct*16 + lm] = f2b(acc[ct][reg]);
  } else {
#pragma unroll
    for (int ct = 0; ct < 4; ++ct)
#pragma unroll
      for (int reg = 0; reg < 4; ++reg) {
        int r = by*64 + r0 + reg;
        int s = r / 80, m = r % 80;
        int d = bxx*64 + ct*16 + lm;
        VT[((size_t)s*256 + d)*80 + m] = f2b(acc[ct][reg]);
      }
  }
}

// ---------------- per-row item layer norm, bf16 out -------------------------
__global__ __launch_bounds__(64) void norm_k(const float* __restrict__ in,
                                             us* __restrict__ out)
{
  const int r = blockIdx.x, t = threadIdx.x;
  float v0 = in[(size_t)r*128 + t];
  float v1 = in[(size_t)r*128 + t + 64];
  float sm = v0 + v1;
#pragma unroll
  for (int off = 1; off < 64; off <<= 1) sm += __shfl_xor(sm, off, 64);
  float mean = sm * (1.0f/128.0f);
  float d0 = v0 - mean, d1 = v1 - mean;
  float vs = d0*d0 + d1*d1;
#pragma unroll
  for (int off = 1; off < 64; off <<= 1) vs += __shfl_xor(vs, off, 64);
  float inv = 1.0f / (sqrtf(vs * (1.0f/128.0f)) + 1e-3f);
  bool keep = (sm != 0.0f);
  out[(size_t)r*128 + t]      = f2b(keep ? d0*inv : 0.0f);
  out[(size_t)r*128 + t + 64] = f2b(keep ? d1*inv : 0.0f);
}

// ---------------- weight prep: Wfc transposes -------------------------------
__global__ __launch_bounds__(256) void wprep_k(const float* __restrict__ Wfc_e,
                                               const float* __restrict__ Wfc_d,
                                               us* __restrict__ WfcTe,
                                               us* __restrict__ WfcTd)
{
  int idx = blockIdx.x*256 + threadIdx.x; // 32768
  if (idx < 16384) {
    int c = idx >> 7, k = idx & 127;
    WfcTe[idx] = f2b(Wfc_e[(size_t)k*128 + c]);
  } else if (idx < 32768) {
    int i2 = idx - 16384; int c = i2 >> 7, k = i2 & 127;
    WfcTd[i2] = f2b(Wfc_d[(size_t)k*128 + c]);
  }
}

// ---------------- Wvh = Wv_h @ Wh_h per head (f32 out, [128][256]) ----------
__global__ __launch_bounds__(128) void wvh_k(const float* __restrict__ Wv,
                                             const float* __restrict__ Wh,
                                             float* __restrict__ Wvh)
{
  int k = blockIdx.x, h = blockIdx.y, c = threadIdx.x;
  float acc = 0.f;
#pragma unroll 8
  for (int d = 0; d < 128; ++d)
    acc = fmaf(Wv[(size_t)k*256 + h*128 + d], Wh[(size_t)(h*128 + d)*128 + c], acc);
  Wvh[(size_t)k*256 + h*128 + c] = acc;
}

// ---------------- M_h = Wcs_h @ Wcs_h^T (symmetric), bf16 out ---------------
__global__ __launch_bounds__(128) void mfold_k(const float* __restrict__ Wcs,
                                               us* __restrict__ Mb)
{
  __shared__ float W[128][129];
  int c = blockIdx.x, h = blockIdx.y, d = threadIdx.x;
  for (int idx = threadIdx.x; idx < 16384; idx += 128) {
    int r = idx >> 7, col = idx & 127;
    W[r][col] = Wcs[(size_t)r*256 + h*128 + col];
  }
  __syncthreads();
  float acc = 0.f;
#pragma unroll 8
  for (int k = 0; k < 128; ++k)
    acc = fmaf(Wcs[(size_t)c*256 + h*128 + k], W[d][k], acc);
  Mb[(size_t)h*16384 + c*128 + d] = f2b(acc);
}

// ---------------- attention block for ordered (a,b), 320 threads ------------
// x4 = base[a] + Sum_h P_h @ VWh_h[b]; z=norm(x4); x4 += gelu(z @ Wfc).
// X: 32KB staging (K [80][256B swz] / VWh [128][160B rot] / Wfc [128][256B swz])
// Y: 20KB wave-local (P, z) — all Y traffic is own-16-row stripe, no barriers.
template<int PERM_RES>
__device__ __forceinline__ void attn4(int a, int b, int t,
    const us* __restrict__ Qg, const us* __restrict__ Kg,
    const us* __restrict__ VTg, const float* __restrict__ baseg,
    const us* __restrict__ WfcT,
    char* __restrict__ X, char* __restrict__ Y, f4v x4[8])
{
  const int wv = t >> 6, lm = t & 15, lh = (t >> 4) & 3;
  const int ar = wv*16 + lm, r0 = wv*16 + lh*4;
  const float isq = 0.08838834764831845f;
#pragma unroll
  for (int dt = 0; dt < 8; ++dt) x4[dt] = (f4v){0.f,0.f,0.f,0.f};

#pragma unroll 1
  for (int h = 0; h < 2; ++h) {
    // prefetch K, VWh, Q into regs (hide global latency behind barriers)
    s8v kv[4], vv[4], qf[4];
#pragma unroll
    for (int q = 0; q < 4; ++q) {
      int qq = t + q*320;
      int rk = qq >> 4, ck = qq & 15;
      kv[q] = *(const s8v*)(Kg + (((size_t)(b*NI + rk)) << 8) + h*128 + (ck << 3));
      int rv = qq / 10, cv = qq - rv*10;
      vv[q] = *(const s8v*)(VTg + ((size_t)(b*256 + h*128 + rv))*80 + (cv << 3));
    }
    {
      const us* qrow = Qg + (((size_t)(a*NI + ar)) << 8) + h*128 + lh*8;
#pragma unroll
      for (int ks = 0; ks < 4; ++ks) qf[ks] = *(const s8v*)(qrow + ks*32);
    }
    __syncthreads();           // previous X readers done
#pragma unroll
    for (int q = 0; q < 4; ++q) {
      int qq = t + q*320;
      int rk = qq >> 4, ck = (qq & 15) << 4;
      *(s8v*)(X + rk*256 + (ck ^ ((rk & 7) << 4))) = kv[q];
    }
    __syncthreads();
    // ---- S = Q K^T ----
    f4v sA[5];
#pragma unroll
    for (int nt = 0; nt < 5; ++nt) {
      int row = nt*16 + lm;
      f4v acc = (f4v){0.f,0.f,0.f,0.f};
#pragma unroll
      for (int ks = 0; ks < 4; ++ks) {
        s8v kf = *(const s8v*)(X + row*256 + ((ks*64 + lh*16) ^ ((row & 7) << 4)));
        acc = MFMA(qf[ks], kf, acc);
      }
      sA[nt] = acc;
    }
    // ---- masked softmax (mask: s!=0; max over raw row) -> P in Y ----
#pragma unroll
    for (int reg = 0; reg < 4; ++reg) {
      int r = r0 + reg;
      float sv[5];
#pragma unroll
      for (int nt = 0; nt < 5; ++nt) sv[nt] = sA[nt][reg] * isq;
      float mx = sv[0];
#pragma unroll
      for (int nt = 1; nt < 5; ++nt) mx = fmaxf(mx, sv[nt]);
#pragma unroll
      for (int off = 1; off < 16; off <<= 1) mx = fmaxf(mx, __shfl_xor(mx, off, 64));
      float e[5], sum = 0.f;
#pragma unroll
      for (int nt = 0; nt < 5; ++nt) {
        e[nt] = (sv[nt] != 0.f) ? __expf(sv[nt] - mx) : 0.f;
        sum += e[nt];
      }
#pragma unroll
      for (int off = 1; off < 16; off <<= 1) sum += __shfl_xor(sum, off, 64);
      float inv = 1.f / (sum + 1e-10f);
#pragma unroll
      for (int nt = 0; nt < 5; ++nt)
        *(us*)(Y + r*256 + ((2*(nt*16 + lm)) ^ ((r & 7) << 4))) = f2b(e[nt] * inv);
    }
    s8v pf0 = *(const s8v*)(Y + ar*256 + ((lh*16) ^ ((ar & 7) << 4)));
    s8v pf1 = *(const s8v*)(Y + ar*256 + ((64 + lh*16) ^ ((ar & 7) << 4)));
    s8v pf2 = zero8();
    if (lh < 2)
      pf2 = *(const s8v*)(Y + ar*256 + ((128 + lh*16) ^ ((ar & 7) << 4)));
    __syncthreads();           // K reads done
#pragma unroll
    for (int q = 0; q < 4; ++q) {
      int qq = t + q*320;
      int rv = qq / 10, cv = qq - rv*10;
      int off = (cv << 4) + ((rv % 10) << 4); if (off >= 160) off -= 160;
      *(s8v*)(X + rv*160 + off) = vv[q];
    }
    __syncthreads();
    // residual prefetch during last head's PV
    f4v rr[8];
    if (PERM_RES && h == 1) {
#pragma unroll
      for (int reg = 0; reg < 4; ++reg) {
        const f4v* bp = (const f4v*)(baseg + (((size_t)(a*NI + r0 + reg)) << 7) + lm*8);
        rr[reg*2] = bp[0]; rr[reg*2+1] = bp[1];
      }
    }
    // ---- x4 += P @ VWh ----
#pragma unroll
    for (int dt = 0; dt < 8; ++dt) {
      int row = dt*16 + lm;
      int rm = (row % 10) << 4;
      int o0 = lh*16 + rm; if (o0 >= 160) o0 -= 160;
      s8v v0 = *(const s8v*)(X + row*160 + o0);
      x4[dt] = MFMA(pf0, v0, x4[dt]);
      int o1 = 64 + lh*16 + rm; if (o1 >= 160) o1 -= 160;
      s8v v1 = *(const s8v*)(X + row*160 + o1);
      x4[dt] = MFMA(pf1, v1, x4[dt]);
      s8v v2 = zero8();
      if (lh < 2) {
        int o2 = 128 + lh*16 + rm; if (o2 >= 160) o2 -= 160;
        v2 = *(const s8v*)(X + row*160 + o2);
      }
      x4[dt] = MFMA(pf2, v2, x4[dt]);
    }
    // ---- residual add on last head ----
    if (h == 1) {
      if (PERM_RES) {
#pragma unroll
        for (int reg = 0; reg < 4; ++reg)
#pragma unroll
          for (int dt = 0; dt < 4; ++dt) {
            x4[dt][reg]   += rr[reg*2][dt];
            x4[dt+4][reg] += rr[reg*2+1][dt];
          }
      } else {
#pragma unroll
        for (int reg = 0; reg < 4; ++reg) {
          int r = r0 + reg;
#pragma unroll
          for (int dt = 0; dt < 8; ++dt)
            x4[dt][reg] += baseg[(((size_t)(a*NI + r)) << 7) + dt*16 + lm];
        }
      }
    }
  } // heads

  // ---- prefetch Wfc while doing norm ----
  s8v wf[7];
#pragma unroll
  for (int q = 0; q < 7; ++q) {
    int qq = t + q*320;
    if (qq < 2048)
      wf[q] = *(const s8v*)(WfcT + ((size_t)(qq >> 4))*128 + ((qq & 15) << 3));
  }
  // ---- z = item_norm(x4) -> Y ----
#pragma unroll
  for (int reg = 0; reg < 4; ++reg) {
    int r = r0 + reg;
    float sm = 0.f;
#pragma unroll
    for (int dt = 0; dt < 8; ++dt) sm += x4[dt][reg];
#pragma unroll
    for (int off = 1; off < 16; off <<= 1) sm += __shfl_xor(sm, off, 64);
    float mean = sm * (1.0f/128.0f);
    float vs = 0.f;
#pragma unroll
    for (int dt = 0; dt < 8; ++dt) { float d = x4[dt][reg] - mean; vs = fmaf(d, d, vs); }
#pragma unroll
    for (int off = 1; off < 16; off <<= 1) vs += __shfl_xor(vs, off, 64);
    float inv = 1.f / (sqrtf(vs * (1.0f/128.0f)) + 1e-3f);
    bool keep = (sm != 0.f);
#pragma unroll
    for (int dt = 0; dt < 8; ++dt)
      *(us*)(Y + r*256 + ((2*(dt*16 + lm)) ^ ((r & 7) << 4))) = f2b(keep ? (x4[dt][reg]-mean)*inv : 0.f);
  }
  __syncthreads();           // PV X reads done
#pragma unroll
  for (int q = 0; q < 7; ++q) {
    int qq = t + q*320;
    if (qq < 2048) {
      int rw = qq >> 4, cw = (qq & 15) << 4;
      *(s8v*)(X + rw*256 + (cw ^ ((rw & 7) << 4))) = wf[q];
    }
  }
  __syncthreads();
  // ---- x4 += gelu(z @ Wfc) ----
  s8v zf[4];
#pragma unroll
  for (int ks = 0; ks < 4; ++ks)
    zf[ks] = *(const s8v*)(Y + ar*256 + ((ks*64 + lh*16) ^ ((ar & 7) << 4)));
#pragma unroll
  for (int dt = 0; dt < 8; ++dt) {
    int row = dt*16 + lm;
    f4v acc = (f4v){0.f,0.f,0.f,0.f};
#pragma unroll
    for (int ks = 0; ks < 4; ++ks) {
      s8v wfr = *(const s8v*)(X + row*256 + ((ks*64 + lh*16) ^ ((row & 7) << 4)));
      acc = MFMA(zf[ks], wfr, acc);
    }
#pragma unroll
    for (int reg = 0; reg < 4; ++reg) x4[dt][reg] += gelu_f(acc[reg]);
  }
}

// ---------------- encoder kernel: per-set self-attention --------------------
__global__ __launch_bounds__(320, 3) void enc_k(
    const us* __restrict__ Qg, const us* __restrict__ Kg,
    const us* __restrict__ VTg, const float* __restrict__ hb,
    const us* __restrict__ WfcT, float* __restrict__ e2p,
    us* __restrict__ z3b)
{
  __shared__ __align__(16) char X[32768];
  __shared__ __align__(16) char Y[20480];
  const int t = threadIdx.x;
  const int wv = t >> 6, lm = t & 15, lh = (t >> 4) & 3;
  const int r0 = wv*16 + lh*4;
  const int i = blockIdx.x;
  f4v x4[8];
  attn4<0>(i, i, t, Qg, Kg, VTg, hb, WfcT, X, Y, x4);
#pragma unroll
  for (int reg = 0; reg < 4; ++reg) {
    int r = r0 + reg;
    size_t gb = ((size_t)(i*NI + r)) << 7;
    float tmp[8]; float sm = 0.f;
#pragma unroll
    for (int dt = 0; dt < 8; ++dt) { tmp[dt] = x4[dt][reg]; sm += tmp[dt]; }
    *(float4*)(e2p + gb + lm*8)     = make_float4(tmp[0],tmp[1],tmp[2],tmp[3]);
    *(float4*)(e2p + gb + lm*8 + 4) = make_float4(tmp[4],tmp[5],tmp[6],tmp[7]);
#pragma unroll
    for (int off = 1; off < 16; off <<= 1) sm += __shfl_xor(sm, off, 64);
    float mean = sm * (1.0f/128.0f);
    float vs = 0.f;
#pragma unroll
    for (int dt = 0; dt < 8; ++dt) { float d = tmp[dt] - mean; vs = fmaf(d, d, vs); }
#pragma unroll
    for (int off = 1; off < 16; off <<= 1) vs += __shfl_xor(vs, off, 64);
    float inv = 1.f / (sqrtf(vs * (1.0f/128.0f)) + 1e-3f);
    bool keep = (sm != 0.f);
#pragma unroll
    for (int dt = 0; dt < 8; ++dt)
      z3b[gb + dt*16 + lm] = f2b(keep ? (tmp[dt]-mean)*inv : 0.f);
  }
}

// ---------------- pair kernel: both orderings + symmetric score -------------
__global__ __launch_bounds__(320, 3) void pair_k(
    const us* __restrict__ Qg, const us* __restrict__ Kg,
    const us* __restrict__ VTg, const float* __restrict__ e2p,
    const us* __restrict__ WfcT, const us* __restrict__ Mb,
    const float* __restrict__ Wcs2, const float* __restrict__ xsg,
    float* __restrict__ outg)
{
  __shared__ __align__(16) char X[32768];
  __shared__ __align__(16) char Y[20480];
  __shared__ __align__(16) char XI[20480];
  __shared__ float red[10];
  const int t = threadIdx.x;
  const int wv = t >> 6, lm = t & 15, lh = (t >> 4) & 3;
  const int ar = wv*16 + lm, r0 = wv*16 + lh*4;
  const float isq = 0.08838834764831845f;

  // triangular decode with XCD-chunk swizzle (1176 = 8*147)
  int bid0 = blockIdx.x;
  int bid = (bid0 & 7) * 147 + (bid0 >> 3);
  int ii = (int)(0.5f*(97.0f - sqrtf(9409.0f - 8.0f*(float)bid)));
  if (ii > 47) ii = 47; if (ii < 0) ii = 0;
  while (ii*SS - ii*(ii-1)/2 > bid) --ii;
  while ((ii+1)*SS - (ii+1)*ii/2 <= bid) ++ii;
  const int i = ii, j = ii + (bid - (ii*SS - ii*(ii-1)/2));

  f4v x4[8];
  attn4<1>(i, j, t, Qg, Kg, VTg, e2p, WfcT, X, Y, x4);
#pragma unroll
  for (int reg = 0; reg < 4; ++reg) {
    int r = r0 + reg;
#pragma unroll
    for (int dt = 0; dt < 8; ++dt)
      *(us*)(XI + r*256 + ((2*(dt*16 + lm)) ^ ((r & 7) << 4))) = f2b(x4[dt][reg]);
  }
  attn4<1>(j, i, t, Qg, Kg, VTg, e2p, WfcT, X, Y, x4);
#pragma unroll
  for (int reg = 0; reg < 4; ++reg) {
    int r = r0 + reg;
#pragma unroll
    for (int dt = 0; dt < 8; ++dt)
      *(us*)(Y + r*256 + ((2*(dt*16 + lm)) ^ ((r & 7) << 4))) = f2b(x4[dt][reg]);
  }
  // x4_ij A-frags (cached for both heads)
  s8v xf[4];
#pragma unroll
  for (int ks = 0; ks < 4; ++ks)
    xf[ks] = *(const s8v*)(XI + ar*256 + ((ks*64 + lh*16) ^ ((ar & 7) << 4)));

  float sc0 = 0.f, sc1 = 0.f;
#pragma unroll 1
  for (int h = 0; h < 2; ++h) {
    // stage M_h (prefetch -> barrier -> write)
    s8v mf[7];
#pragma unroll
    for (int q = 0; q < 7; ++q) {
      int qq = t + q*320;
      if (qq < 2048)
        mf[q] = *(const s8v*)(Mb + (size_t)h*16384 + ((size_t)(qq >> 4))*128 + ((qq & 15) << 3));
    }
    __syncthreads();   // h0: Wfc reads + Y writes done; h1: Yh/G reads done
#pragma unroll
    for (int q = 0; q < 7; ++q) {
      int qq = t + q*320;
      if (qq < 2048) {
        int rw = qq >> 4, cw = (qq & 15) << 4;
        *(s8v*)(X + rw*256 + (cw ^ ((rw & 7) << 4))) = mf[q];
      }
    }
    __syncthreads();
    // Yh = x4_ij @ M_h -> XI (own rows)
#pragma unroll
    for (int dt = 0; dt < 8; ++dt) {
      int row = dt*16 + lm;
      f4v acc = (f4v){0.f,0.f,0.f,0.f};
#pragma unroll
      for (int ks = 0; ks < 4; ++ks) {
        s8v mfr = *(const s8v*)(X + row*256 + ((ks*64 + lh*16) ^ ((row & 7) << 4)));
        acc = MFMA(xf[ks], mfr, acc);
      }
#pragma unroll
      for (int reg = 0; reg < 4; ++reg) {
        int r = r0 + reg;
        *(us*)(XI + r*256 + ((2*(dt*16 + lm)) ^ ((r & 7) << 4))) = f2b(acc[reg]);
      }
    }
    s8v af[4];
#pragma unroll
    for (int ks = 0; ks < 4; ++ks)
      af[ks] = *(const s8v*)(XI + ar*256 + ((ks*64 + lh*16) ^ ((ar & 7) << 4)));
    // G = Yh @ x4_ji^T ; sum relu(G*isq)
    float loc = 0.f;
#pragma unroll
    for (int nt = 0; nt < 5; ++nt) {
      int brow = nt*16 + lm;
      f4v acc = (f4v){0.f,0.f,0.f,0.f};
#pragma unroll
      for (int ks = 0; ks < 4; ++ks) {
        s8v bf = *(const s8v*)(Y + brow*256 + ((ks*64 + lh*16) ^ ((brow & 7) << 4)));
        acc = MFMA(af[ks], bf, acc);
      }
#pragma unroll
      for (int reg = 0; reg < 4; ++reg) loc += fmaxf(acc[reg]*isq, 0.f);
    }
    if (h == 0) sc0 = loc; else sc1 = loc;
  }
#pragma unroll
  for (int off = 1; off < 64; off <<= 1) {
    sc0 += __shfl_xor(sc0, off, 64);
    sc1 += __shfl_xor(sc1, off, 64);
  }
  if ((t & 63) == 0) { red[wv] = sc0; red[wv + 5] = sc1; }
  __syncthreads();
  if (t == 0) {
    float s0 = red[0]+red[1]+red[2]+red[3]+red[4];
    float s1 = red[5]+red[6]+red[7]+red[8]+red[9];
    float val = (s0*Wcs2[0] + s1*Wcs2[1]) / (xsg[i]*xsg[j]);
    outg[i*SS + j] = val;
    outg[j*SS + i] = val;
  }
}

extern "C" void kernel_launch(void* const* d_in, const int* in_sizes, int n_in,
                              void* d_out, int out_size, void* d_ws, size_t ws_size,
                              hipStream_t stream)
{
  (void)in_sizes; (void)n_in; (void)out_size; (void)ws_size;
  const float* x     = (const float*)d_in[0];
  const float* xs    = (const float*)d_in[1];
  const float* W1    = (const float*)d_in[2];
  const float* W2    = (const float*)d_in[3];
  const float* W3    = (const float*)d_in[4];
  const float* Wq_s  = (const float*)d_in[5];
  const float* Wk_s  = (const float*)d_in[6];
  const float* Wv_s  = (const float*)d_in[7];
  const float* Wh_s  = (const float*)d_in[8];
  const float* Wfc_e = (const float*)d_in[9];
  const float* Wq_c  = (const float*)d_in[10];
  const float* Wk_c  = (const float*)d_in[11];
  const float* Wv_c  = (const float*)d_in[12];
  const float* Wh_c  = (const float*)d_in[13];
  const float* Wfc_d = (const float*)d_in[14];
  const float* Wcs   = (const float*)d_in[15];
  const float* Wcs2  = (const float*)d_in[16];
  float* out = (float*)d_out;

  char* w = (char*)d_ws;
  us* h1b     = (us*)w;    w += (size_t)3840*512*2;
  us* h2b     = (us*)w;    w += (size_t)3840*256*2;
  float* hb   = (float*)w; w += (size_t)3840*128*4;
  us* zb16    = (us*)w;    w += (size_t)3840*128*2;
  us* z3b     = (us*)w;    w += (size_t)3840*128*2;
  float* e2p  = (float*)w; w += (size_t)3840*128*4;
  us* Qb      = (us*)w;    w += (size_t)3840*256*2;
  us* Kb      = (us*)w;    w += (size_t)3840*256*2;
  us* VT      = (us*)w;    w += (size_t)48*256*80*2;
  us* WfcTe   = (us*)w;    w += 16384*2;
  us* WfcTd   = (us*)w;    w += 16384*2;
  us* Mb      = (us*)w;    w += 32768*2;
  float* Wvh_s = (float*)w; w += 32768*4;
  float* Wvh_c = (float*)w; w += 32768*4;

  // weight folds + transposes
  hipLaunchKernelGGL(wprep_k, dim3(128), dim3(256), 0, stream, Wfc_e, Wfc_d, WfcTe, WfcTd);
  hipLaunchKernelGGL(wvh_k, dim3(128,2), dim3(128), 0, stream, Wv_s, Wh_s, Wvh_s);
  hipLaunchKernelGGL(wvh_k, dim3(128,2), dim3(128), 0, stream, Wv_c, Wh_c, Wvh_c);
  hipLaunchKernelGGL(mfold_k, dim3(128,2), dim3(128), 0, stream, Wcs, Mb);
  // MLP: h = gelu(gelu(gelu(x@W1)@W2)@W3)
  hipLaunchKernelGGL((mgemm_k<0,0>), dim3(8,60), dim3(256), 0, stream,
                     (const void*)x, W1, (void*)h1b, 512, 512);
  hipLaunchKernelGGL((mgemm_k<1,0>), dim3(4,60), dim3(256), 0, stream,
                     (const void*)h1b, W2, (void*)h2b, 256, 512);
  hipLaunchKernelGGL((mgemm_k<1,1>), dim3(2,60), dim3(256), 0, stream,
                     (const void*)h2b, W3, (void*)hb, 128, 256);
  hipLaunchKernelGGL(norm_k, dim3(3840), dim3(64), 0, stream, hb, zb16);
  // encoder QKV (V folded with Wh)
  hipLaunchKernelGGL(qkv_k, dim3(12,60), dim3(256), 0, stream,
                     zb16, Wq_s, Wk_s, Wvh_s, Qb, Kb, VT);
  // encoder -> e2p (permuted f32), z3b (bf16)
  hipLaunchKernelGGL(enc_k, dim3(48), dim3(320), 0, stream,
                     Qb, Kb, VT, hb, WfcTe, e2p, z3b);
  // decoder QKV
  hipLaunchKernelGGL(qkv_k, dim3(12,60), dim3(256), 0, stream,
                     z3b, Wq_c, Wk_c, Wvh_c, Qb, Kb, VT);
  // pair decoder + symmetric score
  hipLaunchKernelGGL(pair_k, dim3(1176), dim3(320), 0, stream,
                     Qb, Kb, VT, e2p, WfcTd, Mb, Wcs2, xs, out);
}

// Round 5
// 330.780 us; speedup vs baseline: 1.9649x; 1.9649x over previous
//
#include <hip/hip_runtime.h>
#include <hip/hip_bf16.h>

// SetMatchingModel S=48,N=80,D=128,H=2,HS=128.
// v5: staging via global_load_lds (zero staging VGPRs, async DMA to LDS,
// swizzle applied on the per-lane GLOBAL source address; LDS dest linear).
// launch_bounds(320,2) -> no spills (round-4 lesson: (320,3) capped the
// unified VGPR+AGPR file at 170 and spilled ~440MB/dispatch to scratch).

#define SS 48
#define NI 80

typedef unsigned short us;
typedef __attribute__((ext_vector_type(8))) short s8v;   // 8 bf16
typedef __attribute__((ext_vector_type(4))) float f4v;   // 4 f32

#define MFMA(a,b,c) __builtin_amdgcn_mfma_f32_16x16x32_bf16((a),(b),(c),0,0,0)

__device__ __forceinline__ float gelu_f(float x){
  return 0.5f * x * (1.0f + erff(x * 0.7071067811865475f));
}
__device__ __forceinline__ us f2b(float f){
  __hip_bfloat16 b = __float2bfloat16(f);
  return reinterpret_cast<us&>(b);
}
__device__ __forceinline__ s8v zero8(){ s8v v = {0,0,0,0,0,0,0,0}; return v; }
// async global->LDS, 16B per lane; LDS dest = wave-uniform base + lane*16
__device__ __forceinline__ void gl16(const void* g, void* l){
  __builtin_amdgcn_global_load_lds(
      (const __attribute__((address_space(1))) void*)g,
      (__attribute__((address_space(3))) void*)l, 16, 0, 0);
}

// ---------------- bf16 MFMA GEMM: C = gelu(A[M,K] @ B[K,N]) -----------------
template<int ABF16, int OUTF32>
__global__ __launch_bounds__(256) void mgemm_k(const void* __restrict__ Ap,
    const float* __restrict__ B, void* __restrict__ Cp, int N, int K)
{
  __shared__ __align__(16) char lds[10240]; // As[64][80B] + Bs[64][80B]
  char* As = lds; char* Bs = lds + 5120;
  const int t = threadIdx.x;
  const int wv = t >> 6, lm = t & 15, lh = (t >> 4) & 3;
  const int bx = blockIdx.x, by = blockIdx.y;
  const int ar = wv*16 + lm, r0 = wv*16 + lh*4;
  f4v acc[4];
#pragma unroll
  for (int ct = 0; ct < 4; ++ct) acc[ct] = {0.f,0.f,0.f,0.f};
  const int rA = t >> 2, kcA = (t & 3) << 3;
  const int kkB = t >> 3, nnB = (t & 7) << 3;
  for (int k0 = 0; k0 < K; k0 += 32) {
    __syncthreads();
    if (ABF16) {
      s8v v = *(const s8v*)((const us*)Ap + (size_t)(by*64 + rA)*K + k0 + kcA);
      *(s8v*)(As + rA*80 + kcA*2) = v;
    } else {
      const float* ap = (const float*)Ap + (size_t)(by*64 + rA)*K + k0 + kcA;
      float4 v0 = *(const float4*)ap, v1 = *(const float4*)(ap + 4);
      us tmp[8] = {f2b(v0.x),f2b(v0.y),f2b(v0.z),f2b(v0.w),
                   f2b(v1.x),f2b(v1.y),f2b(v1.z),f2b(v1.w)};
      *(s8v*)(As + rA*80 + kcA*2) = *(const s8v*)tmp;
    }
    {
      const float* bp = B + (size_t)(k0 + kkB)*N + bx*64 + nnB;
      float4 w0 = *(const float4*)bp, w1 = *(const float4*)(bp + 4);
      float w8[8] = {w0.x,w0.y,w0.z,w0.w,w1.x,w1.y,w1.z,w1.w};
#pragma unroll
      for (int q = 0; q < 8; ++q)
        *(us*)(Bs + (nnB + q)*80 + kkB*2) = f2b(w8[q]);
    }
    __syncthreads();
    s8v af = *(const s8v*)(As + ar*80 + lh*16);
#pragma unroll
    for (int ct = 0; ct < 4; ++ct) {
      s8v bf = *(const s8v*)(Bs + (ct*16 + lm)*80 + lh*16);
      acc[ct] = MFMA(af, bf, acc[ct]);
    }
  }
#pragma unroll
  for (int ct = 0; ct < 4; ++ct)
#pragma unroll
    for (int reg = 0; reg < 4; ++reg) {
      size_t r = by*64 + r0 + reg;
      int c = bx*64 + ct*16 + lm;
      float v = gelu_f(acc[ct][reg]);
      if (OUTF32) ((float*)Cp)[r*N + c] = v;
      else ((us*)Cp)[r*N + c] = f2b(v);
    }
}

// ---------------- fused QKV GEMM (K=128, N=256 each), V -> VT scatter -------
__global__ __launch_bounds__(256) void qkv_k(const us* __restrict__ A,
    const float* __restrict__ Wq, const float* __restrict__ Wk,
    const float* __restrict__ Wv, us* __restrict__ Qb, us* __restrict__ Kb,
    us* __restrict__ VT)
{
  __shared__ __align__(16) char lds[10240];
  char* As = lds; char* Bs = lds + 5120;
  const int t = threadIdx.x;
  const int wv = t >> 6, lm = t & 15, lh = (t >> 4) & 3;
  const int bx = blockIdx.x, by = blockIdx.y;
  const int sel = bx >> 2, bxx = bx & 3;
  const float* B = sel == 0 ? Wq : (sel == 1 ? Wk : Wv);
  const int ar = wv*16 + lm, r0 = wv*16 + lh*4;
  f4v acc[4];
#pragma unroll
  for (int ct = 0; ct < 4; ++ct) acc[ct] = {0.f,0.f,0.f,0.f};
  const int rA = t >> 2, kcA = (t & 3) << 3;
  const int kkB = t >> 3, nnB = (t & 7) << 3;
#pragma unroll
  for (int k0 = 0; k0 < 128; k0 += 32) {
    __syncthreads();
    {
      s8v v = *(const s8v*)(A + (size_t)(by*64 + rA)*128 + k0 + kcA);
      *(s8v*)(As + rA*80 + kcA*2) = v;
      const float* bp = B + (size_t)(k0 + kkB)*256 + bxx*64 + nnB;
      float4 w0 = *(const float4*)bp, w1 = *(const float4*)(bp + 4);
      float w8[8] = {w0.x,w0.y,w0.z,w0.w,w1.x,w1.y,w1.z,w1.w};
#pragma unroll
      for (int q = 0; q < 8; ++q)
        *(us*)(Bs + (nnB + q)*80 + kkB*2) = f2b(w8[q]);
    }
    __syncthreads();
    s8v af = *(const s8v*)(As + ar*80 + lh*16);
#pragma unroll
    for (int ct = 0; ct < 4; ++ct) {
      s8v bf = *(const s8v*)(Bs + (ct*16 + lm)*80 + lh*16);
      acc[ct] = MFMA(af, bf, acc[ct]);
    }
  }
  if (sel < 2) {
    us* O = sel ? Kb : Qb;
#pragma unroll
    for (int ct = 0; ct < 4; ++ct)
#pragma unroll
      for (int reg = 0; reg < 4; ++reg)
        O[(size_t)(by*64 + r0 + reg)*256 + bxx*64 + ct*16 + lm] = f2b(acc[ct][reg]);
  } else {
#pragma unroll
    for (int ct = 0; ct < 4; ++ct)
#pragma unroll
      for (int reg = 0; reg < 4; ++reg) {
        int r = by*64 + r0 + reg;
        int s = r / 80, m = r % 80;
        int d = bxx*64 + ct*16 + lm;
        VT[((size_t)s*256 + d)*80 + m] = f2b(acc[ct][reg]);
      }
  }
}

// ---------------- per-row item layer norm, bf16 out -------------------------
__global__ __launch_bounds__(64) void norm_k(const float* __restrict__ in,
                                             us* __restrict__ out)
{
  const int r = blockIdx.x, t = threadIdx.x;
  float v0 = in[(size_t)r*128 + t];
  float v1 = in[(size_t)r*128 + t + 64];
  float sm = v0 + v1;
#pragma unroll
  for (int off = 1; off < 64; off <<= 1) sm += __shfl_xor(sm, off, 64);
  float mean = sm * (1.0f/128.0f);
  float d0 = v0 - mean, d1 = v1 - mean;
  float vs = d0*d0 + d1*d1;
#pragma unroll
  for (int off = 1; off < 64; off <<= 1) vs += __shfl_xor(vs, off, 64);
  float inv = 1.0f / (sqrtf(vs * (1.0f/128.0f)) + 1e-3f);
  bool keep = (sm != 0.0f);
  out[(size_t)r*128 + t]      = f2b(keep ? d0*inv : 0.0f);
  out[(size_t)r*128 + t + 64] = f2b(keep ? d1*inv : 0.0f);
}

// ---------------- weight prep: Wfc transposes -------------------------------
__global__ __launch_bounds__(256) void wprep_k(const float* __restrict__ Wfc_e,
                                               const float* __restrict__ Wfc_d,
                                               us* __restrict__ WfcTe,
                                               us* __restrict__ WfcTd)
{
  int idx = blockIdx.x*256 + threadIdx.x; // 32768
  if (idx < 16384) {
    int c = idx >> 7, k = idx & 127;
    WfcTe[idx] = f2b(Wfc_e[(size_t)k*128 + c]);
  } else if (idx < 32768) {
    int i2 = idx - 16384; int c = i2 >> 7, k = i2 & 127;
    WfcTd[i2] = f2b(Wfc_d[(size_t)k*128 + c]);
  }
}

// ---------------- Wvh = Wv_h @ Wh_h per head (f32 out, [128][256]) ----------
__global__ __launch_bounds__(128) void wvh_k(const float* __restrict__ Wv,
                                             const float* __restrict__ Wh,
                                             float* __restrict__ Wvh)
{
  int k = blockIdx.x, h = blockIdx.y, c = threadIdx.x;
  float acc = 0.f;
#pragma unroll 8
  for (int d = 0; d < 128; ++d)
    acc = fmaf(Wv[(size_t)k*256 + h*128 + d], Wh[(size_t)(h*128 + d)*128 + c], acc);
  Wvh[(size_t)k*256 + h*128 + c] = acc;
}

// ---------------- M_h = Wcs_h @ Wcs_h^T (symmetric), bf16 out ---------------
__global__ __launch_bounds__(128) void mfold_k(const float* __restrict__ Wcs,
                                               us* __restrict__ Mb)
{
  __shared__ float W[128][129];
  int c = blockIdx.x, h = blockIdx.y, d = threadIdx.x;
  for (int idx = threadIdx.x; idx < 16384; idx += 128) {
    int r = idx >> 7, col = idx & 127;
    W[r][col] = Wcs[(size_t)r*256 + h*128 + col];
  }
  __syncthreads();
  float acc = 0.f;
#pragma unroll 8
  for (int k = 0; k < 128; ++k)
    acc = fmaf(Wcs[(size_t)c*256 + h*128 + k], W[d][k], acc);
  Mb[(size_t)h*16384 + c*128 + d] = f2b(acc);
}

// ---- staging helpers (per-wave, async; swizzle folded into global src) -----
// K-style tile: [rows][256B], dest swizzled (cb ^ ((row&7)<<4)); 4KB/wave/call
__device__ __forceinline__ void stageK(const us* __restrict__ src256, // row r at src256 + r*256el... caller passes element base with row stride given
    char* __restrict__ X, int wv, int lane, int chunks, int rowstride_el)
{
  // generic: chunk covers 4 rows of 256B; row = chunk*4 + (lane>>4)
#pragma unroll
  for (int c = 0; c < 4; ++c) {
    int chunk = wv*4 + c;
    if (chunk >= chunks) break;
    int row = chunk*4 + (lane >> 4);
    int cb  = (lane & 15) << 4;
    int scb = cb ^ ((row & 7) << 4);
    gl16(src256 + (size_t)row*rowstride_el + (scb >> 1), X + chunk*1024);
  }
}

// ---------------- attention block for ordered (a,b), 320 threads ------------
// x4 = base[a] + Sum_h P_h @ VWh_h[b]; z=norm(x4); x4 += gelu(z @ Wfc).
// X: 32KB staging (K [80][256B swz] / VWh [128][160B rot] / Wfc [128][256B swz])
// Y: 20KB wave-local (P, z).
template<int PERM_RES>
__device__ __forceinline__ void attn4(int a, int b, int t,
    const us* __restrict__ Qg, const us* __restrict__ Kg,
    const us* __restrict__ VTg, const float* __restrict__ baseg,
    const us* __restrict__ WfcT,
    char* __restrict__ X, char* __restrict__ Y, f4v x4[8])
{
  const int wv = t >> 6, lane = t & 63, lm = t & 15, lh = (t >> 4) & 3;
  const int ar = wv*16 + lm, r0 = wv*16 + lh*4;
  const float isq = 0.08838834764831845f;
#pragma unroll
  for (int dt = 0; dt < 8; ++dt) x4[dt] = (f4v){0.f,0.f,0.f,0.f};

#pragma unroll 1
  for (int h = 0; h < 2; ++h) {
    __syncthreads();           // previous X readers done
    // ---- stage K_h[b] -> X (async, swizzled via source) ----
#pragma unroll
    for (int c = 0; c < 4; ++c) {
      int chunk = wv*4 + c;    // 0..19
      int row = chunk*4 + (lane >> 4);
      int scb = ((lane & 15) << 4) ^ ((row & 7) << 4);
      gl16(Kg + (((size_t)(b*NI + row)) << 8) + h*128 + (scb >> 1), X + chunk*1024);
    }
    // Q frags (global, own rows) — issued while K DMA is in flight
    s8v qf[4];
    {
      const us* qrow = Qg + (((size_t)(a*NI + ar)) << 8) + h*128 + lh*8;
#pragma unroll
      for (int ks = 0; ks < 4; ++ks) qf[ks] = *(const s8v*)(qrow + ks*32);
    }
    __syncthreads();           // K staged (barrier drains vmcnt)
    // ---- S = Q K^T ----
    f4v sA[5];
#pragma unroll
    for (int nt = 0; nt < 5; ++nt) {
      int row = nt*16 + lm;
      f4v acc = (f4v){0.f,0.f,0.f,0.f};
#pragma unroll
      for (int ks = 0; ks < 4; ++ks) {
        s8v kf = *(const s8v*)(X + row*256 + ((ks*64 + lh*16) ^ ((row & 7) << 4)));
        acc = MFMA(qf[ks], kf, acc);
      }
      sA[nt] = acc;
    }
    // ---- masked softmax (mask: s!=0; max over raw row) -> P in Y ----
#pragma unroll
    for (int reg = 0; reg < 4; ++reg) {
      int r = r0 + reg;
      float sv[5];
#pragma unroll
      for (int nt = 0; nt < 5; ++nt) sv[nt] = sA[nt][reg] * isq;
      float mx = sv[0];
#pragma unroll
      for (int nt = 1; nt < 5; ++nt) mx = fmaxf(mx, sv[nt]);
#pragma unroll
      for (int off = 1; off < 16; off <<= 1) mx = fmaxf(mx, __shfl_xor(mx, off, 64));
      float e[5], sum = 0.f;
#pragma unroll
      for (int nt = 0; nt < 5; ++nt) {
        e[nt] = (sv[nt] != 0.f) ? __expf(sv[nt] - mx) : 0.f;
        sum += e[nt];
      }
#pragma unroll
      for (int off = 1; off < 16; off <<= 1) sum += __shfl_xor(sum, off, 64);
      float inv = 1.f / (sum + 1e-10f);
#pragma unroll
      for (int nt = 0; nt < 5; ++nt)
        *(us*)(Y + r*256 + ((2*(nt*16 + lm)) ^ ((r & 7) << 4))) = f2b(e[nt] * inv);
    }
    s8v pf0 = *(const s8v*)(Y + ar*256 + ((lh*16) ^ ((ar & 7) << 4)));
    s8v pf1 = *(const s8v*)(Y + ar*256 + ((64 + lh*16) ^ ((ar & 7) << 4)));
    s8v pf2 = zero8();
    if (lh < 2)
      pf2 = *(const s8v*)(Y + ar*256 + ((128 + lh*16) ^ ((ar & 7) << 4)));
    __syncthreads();           // K reads done
    // ---- stage VWh_h[b] -> X ([128][160B], row-rotated; src computed) ----
#pragma unroll
    for (int c = 0; c < 4; ++c) {
      int chunk = wv*4 + c;    // 0..19
      int L = chunk*1024 + lane*16;
      int rv = L / 160;
      int rem = L - rv*160;
      int cv = (rem >> 4) - (rv % 10); if (cv < 0) cv += 10;
      gl16(VTg + ((size_t)(b*256 + h*128 + rv))*80 + (cv << 3), X + chunk*1024);
    }
    __syncthreads();           // VWh staged
    // ---- x4 += P @ VWh ----
#pragma unroll
    for (int dt = 0; dt < 8; ++dt) {
      int row = dt*16 + lm;
      int rm = (row % 10) << 4;
      int o0 = lh*16 + rm; if (o0 >= 160) o0 -= 160;
      s8v v0 = *(const s8v*)(X + row*160 + o0);
      x4[dt] = MFMA(pf0, v0, x4[dt]);
      int o1 = 64 + lh*16 + rm; if (o1 >= 160) o1 -= 160;
      s8v v1 = *(const s8v*)(X + row*160 + o1);
      x4[dt] = MFMA(pf1, v1, x4[dt]);
      s8v v2 = zero8();
      if (lh < 2) {
        int o2 = 128 + lh*16 + rm; if (o2 >= 160) o2 -= 160;
        v2 = *(const s8v*)(X + row*160 + o2);
      }
      x4[dt] = MFMA(pf2, v2, x4[dt]);
    }
    // ---- residual add on last head ----
    if (h == 1) {
      if (PERM_RES) {
#pragma unroll
        for (int reg = 0; reg < 4; ++reg) {
          const f4v* bp = (const f4v*)(baseg + (((size_t)(a*NI + r0 + reg)) << 7) + lm*8);
          f4v b0 = bp[0], b1 = bp[1];
#pragma unroll
          for (int dt = 0; dt < 4; ++dt) {
            x4[dt][reg]   += b0[dt];
            x4[dt+4][reg] += b1[dt];
          }
        }
      } else {
#pragma unroll
        for (int reg = 0; reg < 4; ++reg) {
          int r = r0 + reg;
#pragma unroll
          for (int dt = 0; dt < 8; ++dt)
            x4[dt][reg] += baseg[(((size_t)(a*NI + r)) << 7) + dt*16 + lm];
        }
      }
    }
  } // heads

  __syncthreads();             // PV X reads done
  // ---- stage Wfc -> X (async; overlaps with norm below) ----
  for (int chunk = wv; chunk < 32; chunk += 5) {
    int row = chunk*4 + (lane >> 4);
    int scb = ((lane & 15) << 4) ^ ((row & 7) << 4);
    gl16(WfcT + (size_t)row*128 + (scb >> 1), X + chunk*1024);
  }
  // ---- z = item_norm(x4) -> Y ----
#pragma unroll
  for (int reg = 0; reg < 4; ++reg) {
    int r = r0 + reg;
    float sm = 0.f;
#pragma unroll
    for (int dt = 0; dt < 8; ++dt) sm += x4[dt][reg];
#pragma unroll
    for (int off = 1; off < 16; off <<= 1) sm += __shfl_xor(sm, off, 64);
    float mean = sm * (1.0f/128.0f);
    float vs = 0.f;
#pragma unroll
    for (int dt = 0; dt < 8; ++dt) { float d = x4[dt][reg] - mean; vs = fmaf(d, d, vs); }
#pragma unroll
    for (int off = 1; off < 16; off <<= 1) vs += __shfl_xor(vs, off, 64);
    float inv = 1.f / (sqrtf(vs * (1.0f/128.0f)) + 1e-3f);
    bool keep = (sm != 0.f);
#pragma unroll
    for (int dt = 0; dt < 8; ++dt)
      *(us*)(Y + r*256 + ((2*(dt*16 + lm)) ^ ((r & 7) << 4))) = f2b(keep ? (x4[dt][reg]-mean)*inv : 0.f);
  }
  __syncthreads();             // Wfc staged
  // ---- x4 += gelu(z @ Wfc) ----
  s8v zf[4];
#pragma unroll
  for (int ks = 0; ks < 4; ++ks)
    zf[ks] = *(const s8v*)(Y + ar*256 + ((ks*64 + lh*16) ^ ((ar & 7) << 4)));
#pragma unroll
  for (int dt = 0; dt < 8; ++dt) {
    int row = dt*16 + lm;
    f4v acc = (f4v){0.f,0.f,0.f,0.f};
#pragma unroll
    for (int ks = 0; ks < 4; ++ks) {
      s8v wfr = *(const s8v*)(X + row*256 + ((ks*64 + lh*16) ^ ((row & 7) << 4)));
      acc = MFMA(zf[ks], wfr, acc);
    }
#pragma unroll
    for (int reg = 0; reg < 4; ++reg) x4[dt][reg] += gelu_f(acc[reg]);
  }
}

// ---------------- encoder kernel: per-set self-attention --------------------
__global__ __launch_bounds__(320, 2) void enc_k(
    const us* __restrict__ Qg, const us* __restrict__ Kg,
    const us* __restrict__ VTg, const float* __restrict__ hb,
    const us* __restrict__ WfcT, float* __restrict__ e2p,
    us* __restrict__ z3b)
{
  __shared__ __align__(16) char X[32768];
  __shared__ __align__(16) char Y[20480];
  const int t = threadIdx.x;
  const int wv = t >> 6, lm = t & 15, lh = (t >> 4) & 3;
  const int r0 = wv*16 + lh*4;
  const int i = blockIdx.x;
  f4v x4[8];
  attn4<0>(i, i, t, Qg, Kg, VTg, hb, WfcT, X, Y, x4);
#pragma unroll
  for (int reg = 0; reg < 4; ++reg) {
    int r = r0 + reg;
    size_t gb = ((size_t)(i*NI + r)) << 7;
    float tmp[8]; float sm = 0.f;
#pragma unroll
    for (int dt = 0; dt < 8; ++dt) { tmp[dt] = x4[dt][reg]; sm += tmp[dt]; }
    *(float4*)(e2p + gb + lm*8)     = make_float4(tmp[0],tmp[1],tmp[2],tmp[3]);
    *(float4*)(e2p + gb + lm*8 + 4) = make_float4(tmp[4],tmp[5],tmp[6],tmp[7]);
#pragma unroll
    for (int off = 1; off < 16; off <<= 1) sm += __shfl_xor(sm, off, 64);
    float mean = sm * (1.0f/128.0f);
    float vs = 0.f;
#pragma unroll
    for (int dt = 0; dt < 8; ++dt) { float d = tmp[dt] - mean; vs = fmaf(d, d, vs); }
#pragma unroll
    for (int off = 1; off < 16; off <<= 1) vs += __shfl_xor(vs, off, 64);
    float inv = 1.f / (sqrtf(vs * (1.0f/128.0f)) + 1e-3f);
    bool keep = (sm != 0.f);
#pragma unroll
    for (int dt = 0; dt < 8; ++dt)
      z3b[gb + dt*16 + lm] = f2b(keep ? (tmp[dt]-mean)*inv : 0.f);
  }
}

// ---------------- pair kernel: both orderings + symmetric score -------------
__global__ __launch_bounds__(320, 2) void pair_k(
    const us* __restrict__ Qg, const us* __restrict__ Kg,
    const us* __restrict__ VTg, const float* __restrict__ e2p,
    const us* __restrict__ WfcT, const us* __restrict__ Mb,
    const float* __restrict__ Wcs2, const float* __restrict__ xsg,
    float* __restrict__ outg)
{
  __shared__ __align__(16) char X[32768];
  __shared__ __align__(16) char Y[20480];
  __shared__ __align__(16) char XI[20480];
  __shared__ float red[10];
  const int t = threadIdx.x;
  const int wv = t >> 6, lane = t & 63, lm = t & 15, lh = (t >> 4) & 3;
  const int ar = wv*16 + lm, r0 = wv*16 + lh*4;
  const float isq = 0.08838834764831845f;

  // triangular decode with XCD-chunk swizzle (1176 = 8*147)
  int bid0 = blockIdx.x;
  int bid = (bid0 & 7) * 147 + (bid0 >> 3);
  int ii = (int)(0.5f*(97.0f - sqrtf(9409.0f - 8.0f*(float)bid)));
  if (ii > 47) ii = 47; if (ii < 0) ii = 0;
  while (ii*SS - ii*(ii-1)/2 > bid) --ii;
  while ((ii+1)*SS - (ii+1)*ii/2 <= bid) ++ii;
  const int i = ii, j = ii + (bid - (ii*SS - ii*(ii-1)/2));

  f4v x4[8];
  attn4<1>(i, j, t, Qg, Kg, VTg, e2p, WfcT, X, Y, x4);
#pragma unroll
  for (int reg = 0; reg < 4; ++reg) {
    int r = r0 + reg;
#pragma unroll
    for (int dt = 0; dt < 8; ++dt)
      *(us*)(XI + r*256 + ((2*(dt*16 + lm)) ^ ((r & 7) << 4))) = f2b(x4[dt][reg]);
  }
  attn4<1>(j, i, t, Qg, Kg, VTg, e2p, WfcT, X, Y, x4);
#pragma unroll
  for (int reg = 0; reg < 4; ++reg) {
    int r = r0 + reg;
#pragma unroll
    for (int dt = 0; dt < 8; ++dt)
      *(us*)(Y + r*256 + ((2*(dt*16 + lm)) ^ ((r & 7) << 4))) = f2b(x4[dt][reg]);
  }
  // x4_ij A-frags (cached for both heads)
  s8v xf[4];
#pragma unroll
  for (int ks = 0; ks < 4; ++ks)
    xf[ks] = *(const s8v*)(XI + ar*256 + ((ks*64 + lh*16) ^ ((ar & 7) << 4)));

  float sc0 = 0.f, sc1 = 0.f;
#pragma unroll 1
  for (int h = 0; h < 2; ++h) {
    __syncthreads();   // h0: Wfc/X reads + Y writes done; h1: proj X reads done
    // ---- stage M_h -> X (async) ----
    for (int chunk = wv; chunk < 32; chunk += 5) {
      int row = chunk*4 + (lane >> 4);
      int scb = ((lane & 15) << 4) ^ ((row & 7) << 4);
      gl16(Mb + (size_t)h*16384 + (size_t)row*128 + (scb >> 1), X + chunk*1024);
    }
    __syncthreads();   // M staged
    // Yh = x4_ij @ M_h -> XI (own rows)
#pragma unroll
    for (int dt = 0; dt < 8; ++dt) {
      int row = dt*16 + lm;
      f4v acc = (f4v){0.f,0.f,0.f,0.f};
#pragma unroll
      for (int ks = 0; ks < 4; ++ks) {
        s8v mfr = *(const s8v*)(X + row*256 + ((ks*64 + lh*16) ^ ((row & 7) << 4)));
        acc = MFMA(xf[ks], mfr, acc);
      }
#pragma unroll
      for (int reg = 0; reg < 4; ++reg) {
        int r = r0 + reg;
        *(us*)(XI + r*256 + ((2*(dt*16 + lm)) ^ ((r & 7) << 4))) = f2b(acc[reg]);
      }
    }
    s8v af[4];
#pragma unroll
    for (int ks = 0; ks < 4; ++ks)
      af[ks] = *(const s8v*)(XI + ar*256 + ((ks*64 + lh*16) ^ ((ar & 7) << 4)));
    // G = Yh @ x4_ji^T ; sum relu(G*isq)
    float loc = 0.f;
#pragma unroll
    for (int nt = 0; nt < 5; ++nt) {
      int brow = nt*16 + lm;
      f4v acc = (f4v){0.f,0.f,0.f,0.f};
#pragma unroll
      for (int ks = 0; ks < 4; ++ks) {
        s8v bf = *(const s8v*)(Y + brow*256 + ((ks*64 + lh*16) ^ ((brow & 7) << 4)));
        acc = MFMA(af[ks], bf, acc);
      }
#pragma unroll
      for (int reg = 0; reg < 4; ++reg) loc += fmaxf(acc[reg]*isq, 0.f);
    }
    if (h == 0) sc0 = loc; else sc1 = loc;
  }
#pragma unroll
  for (int off = 1; off < 64; off <<= 1) {
    sc0 += __shfl_xor(sc0, off, 64);
    sc1 += __shfl_xor(sc1, off, 64);
  }
  if ((t & 63) == 0) { red[wv] = sc0; red[wv + 5] = sc1; }
  __syncthreads();
  if (t == 0) {
    float s0 = red[0]+red[1]+red[2]+red[3]+red[4];
    float s1 = red[5]+red[6]+red[7]+red[8]+red[9];
    float val = (s0*Wcs2[0] + s1*Wcs2[1]) / (xsg[i]*xsg[j]);
    outg[i*SS + j] = val;
    outg[j*SS + i] = val;
  }
}

extern "C" void kernel_launch(void* const* d_in, const int* in_sizes, int n_in,
                              void* d_out, int out_size, void* d_ws, size_t ws_size,
                              hipStream_t stream)
{
  (void)in_sizes; (void)n_in; (void)out_size; (void)ws_size;
  const float* x     = (const float*)d_in[0];
  const float* xs    = (const float*)d_in[1];
  const float* W1    = (const float*)d_in[2];
  const float* W2    = (const float*)d_in[3];
  const float* W3    = (const float*)d_in[4];
  const float* Wq_s  = (const float*)d_in[5];
  const float* Wk_s  = (const float*)d_in[6];
  const float* Wv_s  = (const float*)d_in[7];
  const float* Wh_s  = (const float*)d_in[8];
  const float* Wfc_e = (const float*)d_in[9];
  const float* Wq_c  = (const float*)d_in[10];
  const float* Wk_c  = (const float*)d_in[11];
  const float* Wv_c  = (const float*)d_in[12];
  const float* Wh_c  = (const float*)d_in[13];
  const float* Wfc_d = (const float*)d_in[14];
  const float* Wcs   = (const float*)d_in[15];
  const float* Wcs2  = (const float*)d_in[16];
  float* out = (float*)d_out;

  char* w = (char*)d_ws;
  us* h1b     = (us*)w;    w += (size_t)3840*512*2;
  us* h2b     = (us*)w;    w += (size_t)3840*256*2;
  float* hb   = (float*)w; w += (size_t)3840*128*4;
  us* zb16    = (us*)w;    w += (size_t)3840*128*2;
  us* z3b     = (us*)w;    w += (size_t)3840*128*2;
  float* e2p  = (float*)w; w += (size_t)3840*128*4;
  us* Qb      = (us*)w;    w += (size_t)3840*256*2;
  us* Kb      = (us*)w;    w += (size_t)3840*256*2;
  us* VT      = (us*)w;    w += (size_t)48*256*80*2;
  us* WfcTe   = (us*)w;    w += 16384*2;
  us* WfcTd   = (us*)w;    w += 16384*2;
  us* Mb      = (us*)w;    w += 32768*2;
  float* Wvh_s = (float*)w; w += 32768*4;
  float* Wvh_c = (float*)w; w += 32768*4;

  // weight folds + transposes
  hipLaunchKernelGGL(wprep_k, dim3(128), dim3(256), 0, stream, Wfc_e, Wfc_d, WfcTe, WfcTd);
  hipLaunchKernelGGL(wvh_k, dim3(128,2), dim3(128), 0, stream, Wv_s, Wh_s, Wvh_s);
  hipLaunchKernelGGL(wvh_k, dim3(128,2), dim3(128), 0, stream, Wv_c, Wh_c, Wvh_c);
  hipLaunchKernelGGL(mfold_k, dim3(128,2), dim3(128), 0, stream, Wcs, Mb);
  // MLP: h = gelu(gelu(gelu(x@W1)@W2)@W3)
  hipLaunchKernelGGL((mgemm_k<0,0>), dim3(8,60), dim3(256), 0, stream,
                     (const void*)x, W1, (void*)h1b, 512, 512);
  hipLaunchKernelGGL((mgemm_k<1,0>), dim3(4,60), dim3(256), 0, stream,
                     (const void*)h1b, W2, (void*)h2b, 256, 512);
  hipLaunchKernelGGL((mgemm_k<1,1>), dim3(2,60), dim3(256), 0, stream,
                     (const void*)h2b, W3, (void*)hb, 128, 256);
  hipLaunchKernelGGL(norm_k, dim3(3840), dim3(64), 0, stream, hb, zb16);
  // encoder QKV (V folded with Wh)
  hipLaunchKernelGGL(qkv_k, dim3(12,60), dim3(256), 0, stream,
                     zb16, Wq_s, Wk_s, Wvh_s, Qb, Kb, VT);
  // encoder -> e2p (permuted f32), z3b (bf16)
  hipLaunchKernelGGL(enc_k, dim3(48), dim3(320), 0, stream,
                     Qb, Kb, VT, hb, WfcTe, e2p, z3b);
  // decoder QKV
  hipLaunchKernelGGL(qkv_k, dim3(12,60), dim3(256), 0, stream,
                     z3b, Wq_c, Wk_c, Wvh_c, Qb, Kb, VT);
  // pair decoder + symmetric score
  hipLaunchKernelGGL(pair_k, dim3(1176), dim3(320), 0, stream,
                     Qb, Kb, VT, e2p, WfcTd, Mb, Wcs2, xs, out);
}